// Round 2
// baseline (518.488 us; speedup 1.0000x reference)
//
#include <hip/hip_runtime.h>
#include <stdint.h>

// Voxelization, scales {2,4,8,1}.
//  - pow2 dims => scale-s index == scale-1 index >> log2(s), bit-exact in f32
//  - k_key: compute packed keys + partition s1 keys into 512 spatial buckets
//    (LDS multi-split, coalesced flush; R5: bucket id from key>>18, no binsearch)
//  - k_bucket: per bucket, build 32KB s1 region in LDS (LDS atomicOr) and
//    derive s2/s4/s8 regions in-LDS; all global stores coalesced
//  - rank(key) via popcount-prefix; bitmap+prefix interleaved as uint2 pairs
//  - R5: k_uniq fused into k_pref (regions are chunk/block-aligned so the
//    region choice is block-uniform; saves a full 38.5MB pairs re-read)
//  - R5: k_write processes 2 points/thread (8 outstanding gathers for MLP)
// Dispatches: memset(bitmap), memset(counters), key, bucket, sumA, scanB,
//             pref+uniq, write.

#define CHUNK 4096
#define NB    1174
#define TOTALW 4808704
// region word offsets, scale order {2,4,8,1}; chunk boundaries 129,146,149
#define R_S2 0
#define R_S4 528384
#define R_S8 598016
#define R_S1 610304
// bucketing: 512 buckets, each covers 2^18 s1 bits = 8192 words = 8 x1-slices
#define NBUCKET 512
#define BCAP 5120
// 1024 blocks x 2048 points, 8 keys/thread
#define KEYBLOCKS 1024
#define ROUND 2048
#define KPT 8

__device__ __forceinline__ uint32_t cmp2(uint32_t w) {
  // result bit i = w[2i] | w[2i+1]  (32->16; also 16->8 with zero upper)
  w = (w | (w >> 1)) & 0x55555555u;
  w = (w | (w >> 1)) & 0x33333333u;
  w = (w | (w >> 2)) & 0x0F0F0F0Fu;
  w = (w | (w >> 4)) & 0x00FF00FFu;
  w = (w | (w >> 8)) & 0x0000FFFFu;
  return w;
}

// ---- phase 1: keys + bucket partition ----
__global__ __launch_bounds__(256) void k_key(
    const float* __restrict__ pts, const int* __restrict__ bidx, int n,
    uint32_t* __restrict__ keys, uint32_t* __restrict__ bitmap,
    uint32_t* __restrict__ bucketCount, uint32_t* __restrict__ bucketData) {
  __shared__ uint32_t cnt[NBUCKET], inc[NBUCKET], pos[NBUCKET], gpos[NBUCKET];
  __shared__ uint32_t shs[256];
  __shared__ uint32_t scratch[ROUND];
  int t = threadIdx.x;
  int base = blockIdx.x * ROUND;

  cnt[t] = 0; cnt[t + 256] = 0;
  pos[t] = 0; pos[t + 256] = 0;
  __syncthreads();

  uint32_t myKey[KPT];
  int myBk[KPT];
#pragma unroll
  for (int k = 0; k < KPT; k++) {
    int j = base + k * 256 + t;
    myBk[k] = -1;
    if (j < n) {
      float px = pts[3 * j + 0];
      float py = pts[3 * j + 1];
      float pz = pts[3 * j + 2];
      int b = bidx[j];
      // exact reference arithmetic at scale 1 (f32 mul, add, div, trunc)
      int x1 = (int)((512.0f * (px + 51.2f)) / 102.4f);
      int y1 = (int)((512.0f * (py + 51.2f)) / 102.4f);
      int z1 = (int)((64.0f * (pz + 4.0f)) / 6.4f);
      keys[j] = ((uint32_t)b << 27) | ((uint32_t)x1 << 17) | ((uint32_t)y1 << 7) | (uint32_t)z1;
      uint32_t s1k = (uint32_t)(((b * 512 + x1) * 512 + y1) * 64 + z1);
      if (s1k >= (1u << 27)) {
        // fold-over edge (prob ~0): direct atomics into padding words
        atomicOr(&bitmap[R_S1 + (s1k >> 5)], 1u << (s1k & 31u));
        uint32_t k2 = (uint32_t)(((b * 256 + (x1 >> 1)) * 256 + (y1 >> 1)) * 32 + (z1 >> 1));
        atomicOr(&bitmap[R_S2 + (k2 >> 5)], 1u << (k2 & 31u));
        uint32_t k4 = (uint32_t)(((b * 128 + (x1 >> 2)) * 128 + (y1 >> 2)) * 16 + (z1 >> 2));
        atomicOr(&bitmap[R_S4 + (k4 >> 5)], 1u << (k4 & 31u));
        uint32_t k8 = (uint32_t)(((b * 64 + (x1 >> 3)) * 64 + (y1 >> 3)) * 8 + (z1 >> 3));
        atomicOr(&bitmap[R_S8 + (k8 >> 5)], 1u << (k8 & 31u));
      } else {
        int bk = (int)(s1k >> 18);
        myBk[k] = bk;
        myKey[k] = s1k;
        atomicAdd(&cnt[bk], 1u);
      }
    }
  }
  __syncthreads();

  // global reservation (cnt final)
  uint32_t c0 = cnt[2 * t], c1 = cnt[2 * t + 1];
  gpos[2 * t] = c0 ? atomicAdd(&bucketCount[2 * t], c0) : 0u;
  gpos[2 * t + 1] = c1 ? atomicAdd(&bucketCount[2 * t + 1], c1) : 0u;
  // inclusive scan of cnt -> inc (pairwise + 256-scan)
  uint32_t s = c0 + c1;
  shs[t] = s;
  __syncthreads();
  for (int off = 1; off < 256; off <<= 1) {
    uint32_t add = (t >= off) ? shs[t - off] : 0u;
    __syncthreads();
    shs[t] += add;
    __syncthreads();
  }
  inc[2 * t] = shs[t] - s + c0;
  inc[2 * t + 1] = shs[t];
  __syncthreads();
  uint32_t total = shs[255];

  // scatter into bucket-contiguous LDS scratch
#pragma unroll
  for (int k = 0; k < KPT; k++) {
    if (myBk[k] >= 0) {
      int bk = myBk[k];
      uint32_t slot = inc[bk] - cnt[bk] + atomicAdd(&pos[bk], 1u);
      scratch[slot] = myKey[k];
    }
  }
  __syncthreads();

  // flush: consecutive p -> contiguous global per bucket.
  // R5: bucket id is encoded in the key itself (key>>18) -- no binary search,
  // the 9-step dependent LDS chain becomes 1 scratch read + 3 parallel reads.
#pragma unroll
  for (int m = 0; m < KPT; m++) {
    uint32_t p = (uint32_t)(m * 256 + t);
    if (p < total) {
      uint32_t kk = scratch[p];
      int lo = (int)(kk >> 18);
      uint32_t lidx = p - (inc[lo] - cnt[lo]);
      uint32_t g = gpos[lo] + lidx;
      if (g < BCAP) bucketData[(size_t)lo * BCAP + g] = kk;
    }
  }
}

// ---- phase 2: per-bucket LDS bitmap build + in-LDS downsample ----
__global__ __launch_bounds__(256) void k_bucket(
    const uint32_t* __restrict__ bucketCount, const uint32_t* __restrict__ bucketData,
    uint32_t* __restrict__ bitmap) {
  __shared__ uint32_t s1L[8192];
  __shared__ uint32_t s2L[1024];
  __shared__ uint32_t s4L[128];
  int bk = blockIdx.x, t = threadIdx.x;

  uint4 z4 = make_uint4(0, 0, 0, 0);
  for (int i = t; i < 2048; i += 256) ((uint4*)s1L)[i] = z4;
  __syncthreads();

  uint32_t c = bucketCount[bk];
  if (c > BCAP) c = BCAP;
  const uint32_t* src = bucketData + (size_t)bk * BCAP;
  for (uint32_t i = t; i < c; i += 256) {
    uint32_t key = src[i];
    uint32_t local = key & 0x3FFFFu;  // 2^18 bits per bucket
    atomicOr(&s1L[local >> 5], 1u << (local & 31u));
  }
  __syncthreads();

  // write s1 region (coalesced)
  uint4* g1 = (uint4*)(bitmap + R_S1 + (size_t)bk * 8192);
  for (int i = t; i < 2048; i += 256) g1[i] = ((uint4*)s1L)[i];

  // s2 from s1 (local layout: s1 word = (x1rel*512 + y1)*2 + h, x1rel in [0,8))
  for (int i = t; i < 1024; i += 256) {
    int x2r = i >> 8, Y2 = i & 255;
    int a = (2 * x2r * 512 + 2 * Y2) * 2;
    int b2 = ((2 * x2r + 1) * 512 + 2 * Y2) * 2;
    uint32_t Ax = s1L[a], Ay = s1L[a + 1], Az = s1L[a + 2], Aw = s1L[a + 3];
    uint32_t Bx = s1L[b2], By = s1L[b2 + 1], Bz = s1L[b2 + 2], Bw = s1L[b2 + 3];
    s2L[i] = cmp2(Ax | Az | Bx | Bz) | (cmp2(Ay | Aw | By | Bw) << 16);
  }
  __syncthreads();
  for (int i = t; i < 1024; i += 256) bitmap[R_S2 + (size_t)bk * 1024 + i] = s2L[i];

  // s4 from s2 (s2 local: x2rel*256 + y2, x2rel in [0,4))
  if (t < 128) {
    int x4r = t >> 6, kk = t & 63;
    int a = (2 * x4r) * 256 + 4 * kk;
    int b4 = (2 * x4r + 1) * 256 + 4 * kk;
    uint32_t A0 = s2L[a], A1 = s2L[a + 1], A2 = s2L[a + 2], A3 = s2L[a + 3];
    uint32_t B0 = s2L[b4], B1 = s2L[b4 + 1], B2 = s2L[b4 + 2], B3 = s2L[b4 + 3];
    s4L[t] = cmp2(A0 | A1 | B0 | B1) | (cmp2(A2 | A3 | B2 | B3) << 16);
  }
  __syncthreads();
  if (t < 128) bitmap[R_S4 + (size_t)bk * 128 + t] = s4L[t];

  // s8 from s4 (s4 local: x4rel*64 + kk, x4rel in {0,1})
  if (t < 16) {
    uint32_t res = 0;
#pragma unroll
    for (int j = 0; j < 4; j++) {
      uint32_t u = s4L[4 * t + j] | s4L[64 + 4 * t + j];
      u = (u | (u >> 16)) & 0xFFFFu;
      res |= cmp2(u) << (8 * j);
    }
    bitmap[R_S8 + (size_t)bk * 16 + t] = res;
  }
}

// ---- scan / rank infrastructure ----
__global__ __launch_bounds__(256) void k_sumA(
    const uint32_t* __restrict__ bitmap, uint32_t* __restrict__ blockSums) {
  __shared__ uint32_t sh[256];
  int t = threadIdx.x;
  const uint4* bp = (const uint4*)(bitmap + (size_t)blockIdx.x * CHUNK + t * 16);
  uint32_t s = 0;
#pragma unroll
  for (int k = 0; k < 4; k++) {
    uint4 v = bp[k];
    s += __popc(v.x) + __popc(v.y) + __popc(v.z) + __popc(v.w);
  }
  sh[t] = s;
  __syncthreads();
  for (int off = 128; off > 0; off >>= 1) {
    if (t < off) sh[t] += sh[t + off];
    __syncthreads();
  }
  if (t == 0) blockSums[blockIdx.x] = sh[0];
}

__global__ __launch_bounds__(256) void k_scanB(
    uint32_t* blockSums, long long* devOff, uint32_t* devRank, long long fiveN) {
  __shared__ uint32_t sh[256];
  __shared__ uint32_t shB[3];
  int t = threadIdx.x;
  uint32_t v[8];
  uint32_t s = 0;
#pragma unroll
  for (int k = 0; k < 8; k++) {
    int idx = t * 8 + k;
    uint32_t x = (idx < NB) ? blockSums[idx] : 0u;
    v[k] = x;
    s += x;
  }
  sh[t] = s;
  __syncthreads();
  for (int off = 1; off < 256; off <<= 1) {
    uint32_t add = (t >= off) ? sh[t - off] : 0u;
    __syncthreads();
    sh[t] += add;
    __syncthreads();
  }
  uint32_t run = sh[t] - s;
#pragma unroll
  for (int k = 0; k < 8; k++) {
    int idx = t * 8 + k;
    if (idx < NB) blockSums[idx] = run;
    if (idx == 129) shB[0] = run;
    if (idx == 146) shB[1] = run;
    if (idx == 149) shB[2] = run;
    run += v[k];
  }
  __syncthreads();
  if (t == 0) {
    uint32_t tot = sh[255];
    uint32_t T0 = shB[0];
    uint32_t T1 = shB[1] - shB[0];
    uint32_t T2 = shB[2] - shB[1];
    uint32_t T3 = tot - shB[2];
    devOff[0] = 0;
    devOff[1] = devOff[0] + fiveN + 4LL * T0;
    devOff[2] = devOff[1] + fiveN + 4LL * T1;
    devOff[3] = devOff[2] + fiveN + 4LL * T2;
    devOff[4] = devOff[3] + fiveN + 4LL * T3;
    devRank[0] = 0;
    devRank[1] = shB[0];
    devRank[2] = shB[1];
    devRank[3] = shB[2];
  }
}

// bit-decode of one word's set bits -> unique coors rows
template <int LZ, int LYZ, int LB, int MZ, int MY, int MX, int RG, int SCALE_IDX>
__device__ __forceinline__ void decode_word(
    uint32_t w, uint32_t wd, uint32_t pf, uint32_t rankBase,
    const long long* __restrict__ devOff, int* __restrict__ out, long long fiveN) {
  uint32_t pos = pf - rankBase;
  long long base = devOff[SCALE_IDX] + fiveN;
  uint32_t local = w - (uint32_t)RG;
  while (wd) {
    int bit = __ffs(wd) - 1;
    wd &= wd - 1u;
    uint32_t key = (local << 5) + (uint32_t)bit;
    int z = (int)(key & (uint32_t)MZ);
    int y = (int)((key >> LZ) & (uint32_t)MY);
    int x = (int)((key >> LYZ) & (uint32_t)MX);
    int bb = (int)(key >> LB);
    *(int4*)(out + base + 4LL * pos) = make_int4(bb, z, y, x);
    pos++;
  }
}

// ---- fused pref + uniq: compute per-word prefix pairs AND emit unique rows.
// Regions are chunk-aligned at blocks 129/146/149, so the template choice is
// block-uniform (no divergence, __syncthreads inside is safe).
template <int LZ, int LYZ, int LB, int MZ, int MY, int MX, int RG, int SCALE_IDX>
__device__ __forceinline__ void pref_uniq_body(
    const uint32_t* __restrict__ bitmap, const uint32_t* __restrict__ blockSums,
    uint2* __restrict__ pairs, const uint32_t* __restrict__ devRank,
    const long long* __restrict__ devOff, int* __restrict__ out, long long fiveN) {
  __shared__ uint32_t sh[256];
  int t = threadIdx.x;
  size_t w0 = (size_t)blockIdx.x * CHUNK + t * 16;
  const uint4* bp = (const uint4*)(bitmap + w0);
  uint4 words[4];
  uint32_t s = 0;
#pragma unroll
  for (int k = 0; k < 4; k++) {
    uint4 v = bp[k];
    words[k] = v;
    s += __popc(v.x) + __popc(v.y) + __popc(v.z) + __popc(v.w);
  }
  sh[t] = s;
  __syncthreads();
  for (int off = 1; off < 256; off <<= 1) {
    uint32_t add = (t >= off) ? sh[t - off] : 0u;
    __syncthreads();
    sh[t] += add;
    __syncthreads();
  }
  uint32_t run = blockSums[blockIdx.x] + (sh[t] - s);
  uint32_t rankBase = devRank[SCALE_IDX];
  uint4* pp = (uint4*)(pairs + w0);
#pragma unroll
  for (int k = 0; k < 4; k++) {
    uint4 o1, o2;
    uint32_t wa = words[k].x, wb = words[k].y, wc = words[k].z, wdd = words[k].w;
    o1.x = wa; o1.y = run;
    if (wa) decode_word<LZ, LYZ, LB, MZ, MY, MX, RG, SCALE_IDX>(
        (uint32_t)(w0 + 4 * k + 0), wa, run, rankBase, devOff, out, fiveN);
    run += __popc(wa);
    o1.z = wb; o1.w = run;
    if (wb) decode_word<LZ, LYZ, LB, MZ, MY, MX, RG, SCALE_IDX>(
        (uint32_t)(w0 + 4 * k + 1), wb, run, rankBase, devOff, out, fiveN);
    run += __popc(wb);
    o2.x = wc; o2.y = run;
    if (wc) decode_word<LZ, LYZ, LB, MZ, MY, MX, RG, SCALE_IDX>(
        (uint32_t)(w0 + 4 * k + 2), wc, run, rankBase, devOff, out, fiveN);
    run += __popc(wc);
    o2.z = wdd; o2.w = run;
    if (wdd) decode_word<LZ, LYZ, LB, MZ, MY, MX, RG, SCALE_IDX>(
        (uint32_t)(w0 + 4 * k + 3), wdd, run, rankBase, devOff, out, fiveN);
    run += __popc(wdd);
    pp[2 * k] = o1;
    pp[2 * k + 1] = o2;
  }
}

__global__ __launch_bounds__(256) void k_pref_uniq(
    const uint32_t* __restrict__ bitmap, const uint32_t* __restrict__ blockSums,
    uint2* __restrict__ pairs, const uint32_t* __restrict__ devRank,
    const long long* __restrict__ devOff, int* __restrict__ out, long long fiveN) {
  if (blockIdx.x < 129) {
    pref_uniq_body<5, 13, 21, 31, 255, 255, R_S2, 0>(bitmap, blockSums, pairs, devRank, devOff, out, fiveN);
  } else if (blockIdx.x < 146) {
    pref_uniq_body<4, 11, 18, 15, 127, 127, R_S4, 1>(bitmap, blockSums, pairs, devRank, devOff, out, fiveN);
  } else if (blockIdx.x < 149) {
    pref_uniq_body<3, 9, 15, 7, 63, 63, R_S8, 2>(bitmap, blockSums, pairs, devRank, devOff, out, fiveN);
  } else {
    pref_uniq_body<6, 15, 24, 63, 511, 511, R_S1, 3>(bitmap, blockSums, pairs, devRank, devOff, out, fiveN);
  }
}

// ---- per-point outputs: full_coors + inverse via rank lookup ----
// R5: 2 points/thread for doubled gather MLP (8 outstanding 8B loads).
__global__ __launch_bounds__(256) void k_write(
    const uint32_t* __restrict__ keys, int n, const uint2* __restrict__ pairs,
    const uint32_t* __restrict__ devRank, const long long* __restrict__ devOff,
    int* __restrict__ out, long long fourN) {
  const int SX[4] = {256, 128, 64, 512};
  const int SY[4] = {256, 128, 64, 512};
  const int SZ[4] = {32, 16, 8, 64};
  const int SH[4] = {1, 2, 3, 0};
  const int RG[4] = {R_S2, R_S4, R_S8, R_S1};
#pragma unroll
  for (int half = 0; half < 2; half++) {
    int j = blockIdx.x * 512 + half * 256 + threadIdx.x;
    if (j >= n) continue;
    uint32_t p = keys[j];
    int b = (int)(p >> 27);
    int x1 = (int)((p >> 17) & 1023u);
    int y1 = (int)((p >> 7) & 1023u);
    int z1 = (int)(p & 127u);
#pragma unroll
    for (int i = 0; i < 4; i++) {
      int sh = SH[i];
      int xi = x1 >> sh, yi = y1 >> sh, zi = z1 >> sh;
      uint32_t key = (uint32_t)(((b * SX[i] + xi) * SY[i] + yi) * SZ[i] + zi);
      uint2 pr = pairs[RG[i] + (key >> 5)];
      long long o = devOff[i];
      *(int4*)(out + o + 4LL * j) = make_int4(b, xi, yi, zi);
      uint32_t inv = pr.y + __popc(pr.x & ((1u << (key & 31u)) - 1u)) - devRank[i];
      out[o + fourN + j] = (int)inv;
    }
  }
}

extern "C" void kernel_launch(void* const* d_in, const int* in_sizes, int n_in,
                              void* d_out, int out_size, void* d_ws, size_t ws_size,
                              hipStream_t stream) {
  const float* pts = (const float*)d_in[0];
  const int* bidx = (const int*)d_in[1];
  int n = in_sizes[0] / 3;
  int* out = (int*)d_out;

  char* ws = (char*)d_ws;
  long long* devOff = (long long*)ws;                          // 5 * 8 B
  uint32_t* devRank = (uint32_t*)(ws + 64);                    // 4 * 4 B
  uint32_t* chunkSums = (uint32_t*)(ws + 256);                 // NB * 4 B
  uint32_t* bucketCount = (uint32_t*)(ws + 5120);              // 512 * 4 B
  uint32_t* bitmap = (uint32_t*)(ws + 8192);                   // TOTALW * 4 B
  uint2* pairs = (uint2*)(ws + 19243008);                      // TOTALW * 8 B
  uint32_t* keys = (uint32_t*)(ws + 57712640);                 // n * 4 B
  uint32_t* bucketData = (uint32_t*)(ws + 65712640);           // 512 * BCAP * 4 B

  const long long fourN = 4LL * n, fiveN = 5LL * n;
  const int gridW = (n + 511) / 512;

  hipMemsetAsync(bitmap, 0, (size_t)TOTALW * 4, stream);
  hipMemsetAsync(bucketCount, 0, NBUCKET * 4, stream);
  hipLaunchKernelGGL(k_key, dim3(KEYBLOCKS), dim3(256), 0, stream,
                     pts, bidx, n, keys, bitmap, bucketCount, bucketData);
  hipLaunchKernelGGL(k_bucket, dim3(NBUCKET), dim3(256), 0, stream,
                     bucketCount, bucketData, bitmap);
  hipLaunchKernelGGL(k_sumA, dim3(NB), dim3(256), 0, stream, bitmap, chunkSums);
  hipLaunchKernelGGL(k_scanB, dim3(1), dim3(256), 0, stream, chunkSums, devOff, devRank, fiveN);
  hipLaunchKernelGGL(k_pref_uniq, dim3(NB), dim3(256), 0, stream,
                     bitmap, chunkSums, pairs, devRank, devOff, out, fiveN);
  hipLaunchKernelGGL(k_write, dim3(gridW), dim3(256), 0, stream,
                     keys, n, pairs, devRank, devOff, out, fourN);
}

// Round 3
// 449.369 us; speedup vs baseline: 1.1538x; 1.1538x over previous
//
#include <hip/hip_runtime.h>
#include <stdint.h>

// Voxelization, scales {2,4,8,1}.
//  - pow2 dims => scale-s index == scale-1 index >> log2(s), bit-exact in f32
//  - k_key: compute packed keys + partition s1 keys into 512 spatial buckets
//    (LDS multi-split, coalesced flush; bucket id from key>>18, no binsearch)
//    R6: fold-over path removed (provably dead: b<=7,x1,y1<=511,z1<=63 =>
//    s1k < 2^27 always), bitmap arg dropped.
//  - k_bucket: per bucket, build 32KB s1 region in LDS (LDS atomicOr) and
//    derive s2/s4/s8 regions in-LDS; all global stores coalesced.
//    R6: also emits per-chunk popcount sums (k_sumA deleted) and zeroes the
//    4 pad chunks (big bitmap memset deleted -- k_bucket covers every data
//    word of all regions).
//  - rank(key) via popcount-prefix; bitmap+prefix interleaved as uint2 pairs
//  - R6: k_pref / k_uniq back to separate flat passes (R5 fusion regressed
//    -69us: decode serialization behind the prefix pass).
//  - k_write: 2 points/thread (8 outstanding gathers), devOff/devRank
//    preloaded to registers.
// Dispatches: memset(chunkSums), memset(bucketCount), key, bucket, scanB,
//             pref, write, uniq.  (8 total)

#define CHUNK 4096
#define NB    1174
#define TOTALW 4808704
// region word offsets, scale order {2,4,8,1}; chunk boundaries 129,146,149
#define R_S2 0
#define R_S4 528384
#define R_S8 598016
#define R_S1 610304
// pad chunks (zeroed in k_bucket, never written by data paths)
#define PAD0 524288
#define PAD1 593920
#define PAD2 606208
#define PAD3 4804608
// bucketing: 512 buckets, each covers 2^18 s1 bits = 8192 words = 8 x1-slices
#define NBUCKET 512
#define BCAP 5120
// 1024 blocks x 2048 points, 8 keys/thread
#define KEYBLOCKS 1024
#define ROUND 2048
#define KPT 8

__device__ __forceinline__ uint32_t cmp2(uint32_t w) {
  // result bit i = w[2i] | w[2i+1]  (32->16; also 16->8 with zero upper)
  w = (w | (w >> 1)) & 0x55555555u;
  w = (w | (w >> 1)) & 0x33333333u;
  w = (w | (w >> 2)) & 0x0F0F0F0Fu;
  w = (w | (w >> 4)) & 0x00FF00FFu;
  w = (w | (w >> 8)) & 0x0000FFFFu;
  return w;
}

// ---- phase 1: keys + bucket partition ----
__global__ __launch_bounds__(256) void k_key(
    const float* __restrict__ pts, const int* __restrict__ bidx, int n,
    uint32_t* __restrict__ keys,
    uint32_t* __restrict__ bucketCount, uint32_t* __restrict__ bucketData) {
  __shared__ uint32_t cnt[NBUCKET], inc[NBUCKET], pos[NBUCKET], gpos[NBUCKET];
  __shared__ uint32_t shs[256];
  __shared__ uint32_t scratch[ROUND];
  int t = threadIdx.x;
  int base = blockIdx.x * ROUND;

  cnt[t] = 0; cnt[t + 256] = 0;
  pos[t] = 0; pos[t + 256] = 0;
  __syncthreads();

  uint32_t myKey[KPT];
  int myBk[KPT];
#pragma unroll
  for (int k = 0; k < KPT; k++) {
    int j = base + k * 256 + t;
    myBk[k] = -1;
    if (j < n) {
      float px = pts[3 * j + 0];
      float py = pts[3 * j + 1];
      float pz = pts[3 * j + 2];
      int b = bidx[j];
      // exact reference arithmetic at scale 1 (f32 mul, add, div, trunc)
      int x1 = (int)((512.0f * (px + 51.2f)) / 102.4f);
      int y1 = (int)((512.0f * (py + 51.2f)) / 102.4f);
      int z1 = (int)((64.0f * (pz + 4.0f)) / 6.4f);
      keys[j] = ((uint32_t)b << 27) | ((uint32_t)x1 << 17) | ((uint32_t)y1 << 7) | (uint32_t)z1;
      uint32_t s1k = (uint32_t)(((b * 512 + x1) * 512 + y1) * 64 + z1);
      if (s1k < (1u << 27)) {  // always true for in-spec inputs; OOB-guard only
        int bk = (int)(s1k >> 18);
        myBk[k] = bk;
        myKey[k] = s1k;
        atomicAdd(&cnt[bk], 1u);
      }
    }
  }
  __syncthreads();

  // global reservation (cnt final)
  uint32_t c0 = cnt[2 * t], c1 = cnt[2 * t + 1];
  gpos[2 * t] = c0 ? atomicAdd(&bucketCount[2 * t], c0) : 0u;
  gpos[2 * t + 1] = c1 ? atomicAdd(&bucketCount[2 * t + 1], c1) : 0u;
  // inclusive scan of cnt -> inc (pairwise + 256-scan)
  uint32_t s = c0 + c1;
  shs[t] = s;
  __syncthreads();
  for (int off = 1; off < 256; off <<= 1) {
    uint32_t add = (t >= off) ? shs[t - off] : 0u;
    __syncthreads();
    shs[t] += add;
    __syncthreads();
  }
  inc[2 * t] = shs[t] - s + c0;
  inc[2 * t + 1] = shs[t];
  __syncthreads();
  uint32_t total = shs[255];

  // scatter into bucket-contiguous LDS scratch
#pragma unroll
  for (int k = 0; k < KPT; k++) {
    if (myBk[k] >= 0) {
      int bk = myBk[k];
      uint32_t slot = inc[bk] - cnt[bk] + atomicAdd(&pos[bk], 1u);
      scratch[slot] = myKey[k];
    }
  }
  __syncthreads();

  // flush: consecutive p -> contiguous global per bucket; bucket id from key
#pragma unroll
  for (int m = 0; m < KPT; m++) {
    uint32_t p = (uint32_t)(m * 256 + t);
    if (p < total) {
      uint32_t kk = scratch[p];
      int lo = (int)(kk >> 18);
      uint32_t lidx = p - (inc[lo] - cnt[lo]);
      uint32_t g = gpos[lo] + lidx;
      if (g < BCAP) bucketData[(size_t)lo * BCAP + g] = kk;
    }
  }
}

// block tree-reduction; valid result on all threads; shR reusable after return
__device__ __forceinline__ uint32_t blockReduce(uint32_t v, uint32_t* shR, int t) {
  shR[t] = v;
  __syncthreads();
  for (int off = 128; off > 0; off >>= 1) {
    if (t < off) shR[t] += shR[t + off];
    __syncthreads();
  }
  uint32_t r = shR[0];
  __syncthreads();
  return r;
}

// ---- phase 2: per-bucket LDS bitmap build + in-LDS downsample + chunk sums ----
__global__ __launch_bounds__(256) void k_bucket(
    const uint32_t* __restrict__ bucketCount, const uint32_t* __restrict__ bucketData,
    uint32_t* __restrict__ bitmap, uint32_t* __restrict__ chunkSums) {
  __shared__ uint32_t s1L[8192];
  __shared__ uint32_t s2L[1024];
  __shared__ uint32_t s4L[128];
  __shared__ uint32_t shR[256];
  int bk = blockIdx.x, t = threadIdx.x;

  uint4 z4 = make_uint4(0, 0, 0, 0);
  for (int i = t; i < 2048; i += 256) ((uint4*)s1L)[i] = z4;

  // zero the 4 pad chunks (blocks 0..3); everything else is fully overwritten
  if (bk < 4) {
    const int pads[4] = {PAD0, PAD1, PAD2, PAD3};
    uint4* pz = (uint4*)(bitmap + pads[bk]);
    for (int i = t; i < 1024; i += 256) pz[i] = z4;
  }
  __syncthreads();

  uint32_t c = bucketCount[bk];
  if (c > BCAP) c = BCAP;
  const uint32_t* src = bucketData + (size_t)bk * BCAP;
  for (uint32_t i = t; i < c; i += 256) {
    uint32_t key = src[i];
    uint32_t local = key & 0x3FFFFu;  // 2^18 bits per bucket
    atomicOr(&s1L[local >> 5], 1u << (local & 31u));
  }
  __syncthreads();

  // write s1 region (coalesced) + accumulate per-half-region popcounts
  uint4* g1 = (uint4*)(bitmap + R_S1 + (size_t)bk * 8192);
  uint32_t pc1a = 0, pc1b = 0;
  for (int i = t; i < 2048; i += 256) {
    uint4 v = ((uint4*)s1L)[i];
    g1[i] = v;
    uint32_t pc = __popc(v.x) + __popc(v.y) + __popc(v.z) + __popc(v.w);
    if (i < 1024) pc1a += pc; else pc1b += pc;
  }

  // s2 from s1 (local layout: s1 word = (x1rel*512 + y1)*2 + h, x1rel in [0,8))
  for (int i = t; i < 1024; i += 256) {
    int x2r = i >> 8, Y2 = i & 255;
    int a = (2 * x2r * 512 + 2 * Y2) * 2;
    int b2 = ((2 * x2r + 1) * 512 + 2 * Y2) * 2;
    uint32_t Ax = s1L[a], Ay = s1L[a + 1], Az = s1L[a + 2], Aw = s1L[a + 3];
    uint32_t Bx = s1L[b2], By = s1L[b2 + 1], Bz = s1L[b2 + 2], Bw = s1L[b2 + 3];
    s2L[i] = cmp2(Ax | Az | Bx | Bz) | (cmp2(Ay | Aw | By | Bw) << 16);
  }
  __syncthreads();
  uint32_t pc2 = 0;
  for (int i = t; i < 1024; i += 256) {
    uint32_t v = s2L[i];
    bitmap[R_S2 + (size_t)bk * 1024 + i] = v;
    pc2 += __popc(v);
  }

  // s4 from s2 (s2 local: x2rel*256 + y2, x2rel in [0,4))
  uint32_t pc4 = 0;
  if (t < 128) {
    int x4r = t >> 6, kk = t & 63;
    int a = (2 * x4r) * 256 + 4 * kk;
    int b4 = (2 * x4r + 1) * 256 + 4 * kk;
    uint32_t A0 = s2L[a], A1 = s2L[a + 1], A2 = s2L[a + 2], A3 = s2L[a + 3];
    uint32_t B0 = s2L[b4], B1 = s2L[b4 + 1], B2 = s2L[b4 + 2], B3 = s2L[b4 + 3];
    uint32_t v = cmp2(A0 | A1 | B0 | B1) | (cmp2(A2 | A3 | B2 | B3) << 16);
    s4L[t] = v;
    pc4 = __popc(v);
  }
  __syncthreads();
  if (t < 128) bitmap[R_S4 + (size_t)bk * 128 + t] = s4L[t];

  // s8 from s4 (s4 local: x4rel*64 + kk, x4rel in {0,1})
  uint32_t pc8 = 0;
  if (t < 16) {
    uint32_t res = 0;
#pragma unroll
    for (int j = 0; j < 4; j++) {
      uint32_t u = s4L[4 * t + j] | s4L[64 + 4 * t + j];
      u = (u | (u >> 16)) & 0xFFFFu;
      res |= cmp2(u) << (8 * j);
    }
    bitmap[R_S8 + (size_t)bk * 16 + t] = res;
    pc8 = __popc(res);
  }

  // chunk sums: s1 chunks are bucket-exclusive (plain store); s2/s4/s8 chunks
  // span 4/32/256 buckets (atomicAdd partials)
  uint32_t S1a = blockReduce(pc1a, shR, t);
  uint32_t S1b = blockReduce(pc1b, shR, t);
  uint32_t S2 = blockReduce(pc2, shR, t);
  uint32_t S4 = blockReduce(pc4, shR, t);
  uint32_t S8 = blockReduce(pc8, shR, t);
  if (t == 0) {
    chunkSums[149 + 2 * bk] = S1a;
    chunkSums[150 + 2 * bk] = S1b;
    atomicAdd(&chunkSums[bk >> 2], S2);
    atomicAdd(&chunkSums[129 + (bk >> 5)], S4);
    atomicAdd(&chunkSums[146 + (bk >> 8)], S8);
  }
}

// ---- scan / rank infrastructure ----
__global__ __launch_bounds__(256) void k_scanB(
    uint32_t* blockSums, long long* devOff, uint32_t* devRank, long long fiveN) {
  __shared__ uint32_t sh[256];
  __shared__ uint32_t shB[3];
  int t = threadIdx.x;
  uint32_t v[8];
  uint32_t s = 0;
#pragma unroll
  for (int k = 0; k < 8; k++) {
    int idx = t * 8 + k;
    uint32_t x = (idx < NB) ? blockSums[idx] : 0u;
    v[k] = x;
    s += x;
  }
  sh[t] = s;
  __syncthreads();
  for (int off = 1; off < 256; off <<= 1) {
    uint32_t add = (t >= off) ? sh[t - off] : 0u;
    __syncthreads();
    sh[t] += add;
    __syncthreads();
  }
  uint32_t run = sh[t] - s;
#pragma unroll
  for (int k = 0; k < 8; k++) {
    int idx = t * 8 + k;
    if (idx < NB) blockSums[idx] = run;
    if (idx == 129) shB[0] = run;
    if (idx == 146) shB[1] = run;
    if (idx == 149) shB[2] = run;
    run += v[k];
  }
  __syncthreads();
  if (t == 0) {
    uint32_t tot = sh[255];
    uint32_t T0 = shB[0];
    uint32_t T1 = shB[1] - shB[0];
    uint32_t T2 = shB[2] - shB[1];
    uint32_t T3 = tot - shB[2];
    devOff[0] = 0;
    devOff[1] = devOff[0] + fiveN + 4LL * T0;
    devOff[2] = devOff[1] + fiveN + 4LL * T1;
    devOff[3] = devOff[2] + fiveN + 4LL * T2;
    devOff[4] = devOff[3] + fiveN + 4LL * T3;
    devRank[0] = 0;
    devRank[1] = shB[0];
    devRank[2] = shB[1];
    devRank[3] = shB[2];
  }
}

__global__ __launch_bounds__(256) void k_pref(
    const uint32_t* __restrict__ bitmap, const uint32_t* __restrict__ blockSums,
    uint2* __restrict__ pairs) {
  __shared__ uint32_t sh[256];
  int t = threadIdx.x;
  size_t w0 = (size_t)blockIdx.x * CHUNK + t * 16;
  const uint4* bp = (const uint4*)(bitmap + w0);
  uint4 words[4];
  uint32_t s = 0;
#pragma unroll
  for (int k = 0; k < 4; k++) {
    uint4 v = bp[k];
    words[k] = v;
    s += __popc(v.x) + __popc(v.y) + __popc(v.z) + __popc(v.w);
  }
  sh[t] = s;
  __syncthreads();
  for (int off = 1; off < 256; off <<= 1) {
    uint32_t add = (t >= off) ? sh[t - off] : 0u;
    __syncthreads();
    sh[t] += add;
    __syncthreads();
  }
  uint32_t run = blockSums[blockIdx.x] + (sh[t] - s);
  uint4* pp = (uint4*)(pairs + w0);
#pragma unroll
  for (int k = 0; k < 4; k++) {
    uint4 o1, o2;
    o1.x = words[k].x; o1.y = run; run += __popc(words[k].x);
    o1.z = words[k].y; o1.w = run; run += __popc(words[k].y);
    o2.x = words[k].z; o2.y = run; run += __popc(words[k].z);
    o2.z = words[k].w; o2.w = run; run += __popc(words[k].w);
    pp[2 * k] = o1;
    pp[2 * k + 1] = o2;
  }
}

// ---- per-point outputs: full_coors + inverse via rank lookup (2 pts/thread) ----
__global__ __launch_bounds__(256) void k_write(
    const uint32_t* __restrict__ keys, int n, const uint2* __restrict__ pairs,
    const uint32_t* __restrict__ devRank, const long long* __restrict__ devOff,
    int* __restrict__ out, long long fourN) {
  const int SX[4] = {256, 128, 64, 512};
  const int SY[4] = {256, 128, 64, 512};
  const int SZ[4] = {32, 16, 8, 64};
  const int SH[4] = {1, 2, 3, 0};
  const int RG[4] = {R_S2, R_S4, R_S8, R_S1};
  long long off[4];
  uint32_t rnk[4];
#pragma unroll
  for (int i = 0; i < 4; i++) { off[i] = devOff[i]; rnk[i] = devRank[i]; }
#pragma unroll
  for (int half = 0; half < 2; half++) {
    int j = blockIdx.x * 512 + half * 256 + threadIdx.x;
    if (j >= n) continue;
    uint32_t p = keys[j];
    int b = (int)(p >> 27);
    int x1 = (int)((p >> 17) & 1023u);
    int y1 = (int)((p >> 7) & 1023u);
    int z1 = (int)(p & 127u);
#pragma unroll
    for (int i = 0; i < 4; i++) {
      int sh = SH[i];
      int xi = x1 >> sh, yi = y1 >> sh, zi = z1 >> sh;
      uint32_t key = (uint32_t)(((b * SX[i] + xi) * SY[i] + yi) * SZ[i] + zi);
      uint2 pr = pairs[RG[i] + (key >> 5)];
      long long o = off[i];
      *(int4*)(out + o + 4LL * j) = make_int4(b, xi, yi, zi);
      uint32_t inv = pr.y + __popc(pr.x & ((1u << (key & 31u)) - 1u)) - rnk[i];
      out[o + fourN + j] = (int)inv;
    }
  }
}

template <int LZ, int LYZ, int LB, int MZ, int MY, int MX, int RG, int SCALE_IDX>
__device__ __forceinline__ void uniq_region(
    uint32_t w, uint32_t wd, uint32_t pf, uint32_t rankBase,
    const long long* __restrict__ devOff, int* __restrict__ out, long long fiveN) {
  uint32_t pos = pf - rankBase;
  long long base = devOff[SCALE_IDX] + fiveN;
  uint32_t local = w - (uint32_t)RG;
  while (wd) {
    int bit = __ffs(wd) - 1;
    wd &= wd - 1u;
    uint32_t key = (local << 5) + (uint32_t)bit;
    int z = (int)(key & (uint32_t)MZ);
    int y = (int)((key >> LZ) & (uint32_t)MY);
    int x = (int)((key >> LYZ) & (uint32_t)MX);
    int bb = (int)(key >> LB);
    *(int4*)(out + base + 4LL * pos) = make_int4(bb, z, y, x);
    pos++;
  }
}

__global__ __launch_bounds__(256) void k_uniq(
    const uint2* __restrict__ pairs, const uint32_t* __restrict__ devRank,
    const long long* __restrict__ devOff, int* __restrict__ out, long long fiveN) {
  uint32_t w = blockIdx.x * 256 + threadIdx.x;  // < TOTALW, regions block-aligned
  uint2 pr = pairs[w];
  if (!pr.x) return;
  if (w < R_S4) {
    uniq_region<5, 13, 21, 31, 255, 255, R_S2, 0>(w, pr.x, pr.y, devRank[0], devOff, out, fiveN);
  } else if (w < R_S8) {
    uniq_region<4, 11, 18, 15, 127, 127, R_S4, 1>(w, pr.x, pr.y, devRank[1], devOff, out, fiveN);
  } else if (w < R_S1) {
    uniq_region<3, 9, 15, 7, 63, 63, R_S8, 2>(w, pr.x, pr.y, devRank[2], devOff, out, fiveN);
  } else {
    uniq_region<6, 15, 24, 63, 511, 511, R_S1, 3>(w, pr.x, pr.y, devRank[3], devOff, out, fiveN);
  }
}

extern "C" void kernel_launch(void* const* d_in, const int* in_sizes, int n_in,
                              void* d_out, int out_size, void* d_ws, size_t ws_size,
                              hipStream_t stream) {
  const float* pts = (const float*)d_in[0];
  const int* bidx = (const int*)d_in[1];
  int n = in_sizes[0] / 3;
  int* out = (int*)d_out;

  char* ws = (char*)d_ws;
  long long* devOff = (long long*)ws;                          // 5 * 8 B
  uint32_t* devRank = (uint32_t*)(ws + 64);                    // 4 * 4 B
  uint32_t* chunkSums = (uint32_t*)(ws + 256);                 // NB * 4 B
  uint32_t* bucketCount = (uint32_t*)(ws + 5120);              // 512 * 4 B
  uint32_t* bitmap = (uint32_t*)(ws + 8192);                   // TOTALW * 4 B
  uint2* pairs = (uint2*)(ws + 19243008);                      // TOTALW * 8 B
  uint32_t* keys = (uint32_t*)(ws + 57712640);                 // n * 4 B
  uint32_t* bucketData = (uint32_t*)(ws + 65712640);           // 512 * BCAP * 4 B

  const long long fourN = 4LL * n, fiveN = 5LL * n;
  const int gridW = (n + 511) / 512;

  hipMemsetAsync(chunkSums, 0, NB * 4, stream);
  hipMemsetAsync(bucketCount, 0, NBUCKET * 4, stream);
  hipLaunchKernelGGL(k_key, dim3(KEYBLOCKS), dim3(256), 0, stream,
                     pts, bidx, n, keys, bucketCount, bucketData);
  hipLaunchKernelGGL(k_bucket, dim3(NBUCKET), dim3(256), 0, stream,
                     bucketCount, bucketData, bitmap, chunkSums);
  hipLaunchKernelGGL(k_scanB, dim3(1), dim3(256), 0, stream, chunkSums, devOff, devRank, fiveN);
  hipLaunchKernelGGL(k_pref, dim3(NB), dim3(256), 0, stream, bitmap, chunkSums, pairs);
  hipLaunchKernelGGL(k_write, dim3(gridW), dim3(256), 0, stream,
                     keys, n, pairs, devRank, devOff, out, fourN);
  hipLaunchKernelGGL(k_uniq, dim3(TOTALW / 256), dim3(256), 0, stream,
                     pairs, devRank, devOff, out, fiveN);
}

// Round 4
// 426.342 us; speedup vs baseline: 1.2161x; 1.0540x over previous
//
#include <hip/hip_runtime.h>
#include <stdint.h>

// Voxelization, scales {2,4,8,1}.
//  - pow2 dims => scale-s index == scale-1 index >> log2(s), bit-exact in f32
//  - k_key: compute packed keys + partition s1 keys into 512 spatial buckets
//    (LDS multi-split, coalesced flush; bucket id from key>>18). Block 0 also
//    zeroes the 150 chunkSums words that need init (R7: memset deleted).
//  - k_bucket: per bucket, build 32KB s1 region in LDS (LDS atomicOr) and
//    derive s2/s4/s8 regions in-LDS; emits per-chunk popcount sums; zeroes
//    the 4 pad chunks.
//  - rank(key) via popcount-prefix; bitmap+prefix interleaved as uint2 pairs
//  - R7: k_write and k_uniq merged into k_out (independent work, disjoint out
//    ranges): write sections per scale (s1 first -- single-region gathers per
//    wave for L2 locality) then uniq decode blocks; overlap fills stalls.
// Dispatches: memset(bucketCount), key, bucket, scanB, pref, out.  (6 total)

#define CHUNK 4096
#define NB    1174
#define TOTALW 4808704
// region word offsets, scale order {2,4,8,1}; chunk boundaries 129,146,149
#define R_S2 0
#define R_S4 528384
#define R_S8 598016
#define R_S1 610304
// pad chunks (zeroed in k_bucket, never written by data paths)
#define PAD0 524288
#define PAD1 593920
#define PAD2 606208
#define PAD3 4804608
// bucketing: 512 buckets, each covers 2^18 s1 bits = 8192 words = 8 x1-slices
#define NBUCKET 512
#define BCAP 5120
// 1024 blocks x 2048 points, 8 keys/thread
#define KEYBLOCKS 1024
#define ROUND 2048
#define KPT 8

__device__ __forceinline__ uint32_t cmp2(uint32_t w) {
  // result bit i = w[2i] | w[2i+1]  (32->16; also 16->8 with zero upper)
  w = (w | (w >> 1)) & 0x55555555u;
  w = (w | (w >> 1)) & 0x33333333u;
  w = (w | (w >> 2)) & 0x0F0F0F0Fu;
  w = (w | (w >> 4)) & 0x00FF00FFu;
  w = (w | (w >> 8)) & 0x0000FFFFu;
  return w;
}

// ---- phase 1: keys + bucket partition ----
__global__ __launch_bounds__(256) void k_key(
    const float* __restrict__ pts, const int* __restrict__ bidx, int n,
    uint32_t* __restrict__ keys,
    uint32_t* __restrict__ bucketCount, uint32_t* __restrict__ bucketData,
    uint32_t* __restrict__ chunkSums) {
  __shared__ uint32_t cnt[NBUCKET], inc[NBUCKET], pos[NBUCKET], gpos[NBUCKET];
  __shared__ uint32_t shs[256];
  __shared__ uint32_t scratch[ROUND];
  int t = threadIdx.x;
  int base = blockIdx.x * ROUND;

  // R7: init the chunkSums words k_bucket accumulates into (runs in an
  // earlier dispatch than k_bucket -> ordering guaranteed by the stream)
  if (blockIdx.x == 0) {
    if (t < 149) chunkSums[t] = 0;
    if (t == 149) chunkSums[1173] = 0;
  }

  cnt[t] = 0; cnt[t + 256] = 0;
  pos[t] = 0; pos[t + 256] = 0;
  __syncthreads();

  uint32_t myKey[KPT];
  int myBk[KPT];
#pragma unroll
  for (int k = 0; k < KPT; k++) {
    int j = base + k * 256 + t;
    myBk[k] = -1;
    if (j < n) {
      float px = pts[3 * j + 0];
      float py = pts[3 * j + 1];
      float pz = pts[3 * j + 2];
      int b = bidx[j];
      // exact reference arithmetic at scale 1 (f32 mul, add, div, trunc)
      int x1 = (int)((512.0f * (px + 51.2f)) / 102.4f);
      int y1 = (int)((512.0f * (py + 51.2f)) / 102.4f);
      int z1 = (int)((64.0f * (pz + 4.0f)) / 6.4f);
      keys[j] = ((uint32_t)b << 27) | ((uint32_t)x1 << 17) | ((uint32_t)y1 << 7) | (uint32_t)z1;
      uint32_t s1k = (uint32_t)(((b * 512 + x1) * 512 + y1) * 64 + z1);
      if (s1k < (1u << 27)) {  // always true for in-spec inputs; OOB-guard only
        int bk = (int)(s1k >> 18);
        myBk[k] = bk;
        myKey[k] = s1k;
        atomicAdd(&cnt[bk], 1u);
      }
    }
  }
  __syncthreads();

  // global reservation (cnt final)
  uint32_t c0 = cnt[2 * t], c1 = cnt[2 * t + 1];
  gpos[2 * t] = c0 ? atomicAdd(&bucketCount[2 * t], c0) : 0u;
  gpos[2 * t + 1] = c1 ? atomicAdd(&bucketCount[2 * t + 1], c1) : 0u;
  // inclusive scan of cnt -> inc (pairwise + 256-scan)
  uint32_t s = c0 + c1;
  shs[t] = s;
  __syncthreads();
  for (int off = 1; off < 256; off <<= 1) {
    uint32_t add = (t >= off) ? shs[t - off] : 0u;
    __syncthreads();
    shs[t] += add;
    __syncthreads();
  }
  inc[2 * t] = shs[t] - s + c0;
  inc[2 * t + 1] = shs[t];
  __syncthreads();
  uint32_t total = shs[255];

  // scatter into bucket-contiguous LDS scratch
#pragma unroll
  for (int k = 0; k < KPT; k++) {
    if (myBk[k] >= 0) {
      int bk = myBk[k];
      uint32_t slot = inc[bk] - cnt[bk] + atomicAdd(&pos[bk], 1u);
      scratch[slot] = myKey[k];
    }
  }
  __syncthreads();

  // flush: consecutive p -> contiguous global per bucket; bucket id from key
#pragma unroll
  for (int m = 0; m < KPT; m++) {
    uint32_t p = (uint32_t)(m * 256 + t);
    if (p < total) {
      uint32_t kk = scratch[p];
      int lo = (int)(kk >> 18);
      uint32_t lidx = p - (inc[lo] - cnt[lo]);
      uint32_t g = gpos[lo] + lidx;
      if (g < BCAP) bucketData[(size_t)lo * BCAP + g] = kk;
    }
  }
}

// block tree-reduction; valid result on all threads; shR reusable after return
__device__ __forceinline__ uint32_t blockReduce(uint32_t v, uint32_t* shR, int t) {
  shR[t] = v;
  __syncthreads();
  for (int off = 128; off > 0; off >>= 1) {
    if (t < off) shR[t] += shR[t + off];
    __syncthreads();
  }
  uint32_t r = shR[0];
  __syncthreads();
  return r;
}

// ---- phase 2: per-bucket LDS bitmap build + in-LDS downsample + chunk sums ----
__global__ __launch_bounds__(256) void k_bucket(
    const uint32_t* __restrict__ bucketCount, const uint32_t* __restrict__ bucketData,
    uint32_t* __restrict__ bitmap, uint32_t* __restrict__ chunkSums) {
  __shared__ uint32_t s1L[8192];
  __shared__ uint32_t s2L[1024];
  __shared__ uint32_t s4L[128];
  __shared__ uint32_t shR[256];
  int bk = blockIdx.x, t = threadIdx.x;

  uint4 z4 = make_uint4(0, 0, 0, 0);
  for (int i = t; i < 2048; i += 256) ((uint4*)s1L)[i] = z4;

  // zero the 4 pad chunks (blocks 0..3); everything else is fully overwritten
  if (bk < 4) {
    const int pads[4] = {PAD0, PAD1, PAD2, PAD3};
    uint4* pz = (uint4*)(bitmap + pads[bk]);
    for (int i = t; i < 1024; i += 256) pz[i] = z4;
  }
  __syncthreads();

  uint32_t c = bucketCount[bk];
  if (c > BCAP) c = BCAP;
  const uint32_t* src = bucketData + (size_t)bk * BCAP;
  for (uint32_t i = t; i < c; i += 256) {
    uint32_t key = src[i];
    uint32_t local = key & 0x3FFFFu;  // 2^18 bits per bucket
    atomicOr(&s1L[local >> 5], 1u << (local & 31u));
  }
  __syncthreads();

  // write s1 region (coalesced) + accumulate per-half-region popcounts
  uint4* g1 = (uint4*)(bitmap + R_S1 + (size_t)bk * 8192);
  uint32_t pc1a = 0, pc1b = 0;
  for (int i = t; i < 2048; i += 256) {
    uint4 v = ((uint4*)s1L)[i];
    g1[i] = v;
    uint32_t pc = __popc(v.x) + __popc(v.y) + __popc(v.z) + __popc(v.w);
    if (i < 1024) pc1a += pc; else pc1b += pc;
  }

  // s2 from s1 (local layout: s1 word = (x1rel*512 + y1)*2 + h, x1rel in [0,8))
  for (int i = t; i < 1024; i += 256) {
    int x2r = i >> 8, Y2 = i & 255;
    int a = (2 * x2r * 512 + 2 * Y2) * 2;
    int b2 = ((2 * x2r + 1) * 512 + 2 * Y2) * 2;
    uint32_t Ax = s1L[a], Ay = s1L[a + 1], Az = s1L[a + 2], Aw = s1L[a + 3];
    uint32_t Bx = s1L[b2], By = s1L[b2 + 1], Bz = s1L[b2 + 2], Bw = s1L[b2 + 3];
    s2L[i] = cmp2(Ax | Az | Bx | Bz) | (cmp2(Ay | Aw | By | Bw) << 16);
  }
  __syncthreads();
  uint32_t pc2 = 0;
  for (int i = t; i < 1024; i += 256) {
    uint32_t v = s2L[i];
    bitmap[R_S2 + (size_t)bk * 1024 + i] = v;
    pc2 += __popc(v);
  }

  // s4 from s2 (s2 local: x2rel*256 + y2, x2rel in [0,4))
  uint32_t pc4 = 0;
  if (t < 128) {
    int x4r = t >> 6, kk = t & 63;
    int a = (2 * x4r) * 256 + 4 * kk;
    int b4 = (2 * x4r + 1) * 256 + 4 * kk;
    uint32_t A0 = s2L[a], A1 = s2L[a + 1], A2 = s2L[a + 2], A3 = s2L[a + 3];
    uint32_t B0 = s2L[b4], B1 = s2L[b4 + 1], B2 = s2L[b4 + 2], B3 = s2L[b4 + 3];
    uint32_t v = cmp2(A0 | A1 | B0 | B1) | (cmp2(A2 | A3 | B2 | B3) << 16);
    s4L[t] = v;
    pc4 = __popc(v);
  }
  __syncthreads();
  if (t < 128) bitmap[R_S4 + (size_t)bk * 128 + t] = s4L[t];

  // s8 from s4 (s4 local: x4rel*64 + kk, x4rel in {0,1})
  uint32_t pc8 = 0;
  if (t < 16) {
    uint32_t res = 0;
#pragma unroll
    for (int j = 0; j < 4; j++) {
      uint32_t u = s4L[4 * t + j] | s4L[64 + 4 * t + j];
      u = (u | (u >> 16)) & 0xFFFFu;
      res |= cmp2(u) << (8 * j);
    }
    bitmap[R_S8 + (size_t)bk * 16 + t] = res;
    pc8 = __popc(res);
  }

  // chunk sums: s1 chunks are bucket-exclusive (plain store); s2/s4/s8 chunks
  // span 4/32/256 buckets (atomicAdd partials)
  uint32_t S1a = blockReduce(pc1a, shR, t);
  uint32_t S1b = blockReduce(pc1b, shR, t);
  uint32_t S2 = blockReduce(pc2, shR, t);
  uint32_t S4 = blockReduce(pc4, shR, t);
  uint32_t S8 = blockReduce(pc8, shR, t);
  if (t == 0) {
    chunkSums[149 + 2 * bk] = S1a;
    chunkSums[150 + 2 * bk] = S1b;
    atomicAdd(&chunkSums[bk >> 2], S2);
    atomicAdd(&chunkSums[129 + (bk >> 5)], S4);
    atomicAdd(&chunkSums[146 + (bk >> 8)], S8);
  }
}

// ---- scan / rank infrastructure ----
__global__ __launch_bounds__(256) void k_scanB(
    uint32_t* blockSums, long long* devOff, uint32_t* devRank, long long fiveN) {
  __shared__ uint32_t sh[256];
  __shared__ uint32_t shB[3];
  int t = threadIdx.x;
  uint32_t v[8];
  uint32_t s = 0;
#pragma unroll
  for (int k = 0; k < 8; k++) {
    int idx = t * 8 + k;
    uint32_t x = (idx < NB) ? blockSums[idx] : 0u;
    v[k] = x;
    s += x;
  }
  sh[t] = s;
  __syncthreads();
  for (int off = 1; off < 256; off <<= 1) {
    uint32_t add = (t >= off) ? sh[t - off] : 0u;
    __syncthreads();
    sh[t] += add;
    __syncthreads();
  }
  uint32_t run = sh[t] - s;
#pragma unroll
  for (int k = 0; k < 8; k++) {
    int idx = t * 8 + k;
    if (idx < NB) blockSums[idx] = run;
    if (idx == 129) shB[0] = run;
    if (idx == 146) shB[1] = run;
    if (idx == 149) shB[2] = run;
    run += v[k];
  }
  __syncthreads();
  if (t == 0) {
    uint32_t tot = sh[255];
    uint32_t T0 = shB[0];
    uint32_t T1 = shB[1] - shB[0];
    uint32_t T2 = shB[2] - shB[1];
    uint32_t T3 = tot - shB[2];
    devOff[0] = 0;
    devOff[1] = devOff[0] + fiveN + 4LL * T0;
    devOff[2] = devOff[1] + fiveN + 4LL * T1;
    devOff[3] = devOff[2] + fiveN + 4LL * T2;
    devOff[4] = devOff[3] + fiveN + 4LL * T3;
    devRank[0] = 0;
    devRank[1] = shB[0];
    devRank[2] = shB[1];
    devRank[3] = shB[2];
  }
}

__global__ __launch_bounds__(256) void k_pref(
    const uint32_t* __restrict__ bitmap, const uint32_t* __restrict__ blockSums,
    uint2* __restrict__ pairs) {
  __shared__ uint32_t sh[256];
  int t = threadIdx.x;
  size_t w0 = (size_t)blockIdx.x * CHUNK + t * 16;
  const uint4* bp = (const uint4*)(bitmap + w0);
  uint4 words[4];
  uint32_t s = 0;
#pragma unroll
  for (int k = 0; k < 4; k++) {
    uint4 v = bp[k];
    words[k] = v;
    s += __popc(v.x) + __popc(v.y) + __popc(v.z) + __popc(v.w);
  }
  sh[t] = s;
  __syncthreads();
  for (int off = 1; off < 256; off <<= 1) {
    uint32_t add = (t >= off) ? sh[t - off] : 0u;
    __syncthreads();
    sh[t] += add;
    __syncthreads();
  }
  uint32_t run = blockSums[blockIdx.x] + (sh[t] - s);
  uint4* pp = (uint4*)(pairs + w0);
#pragma unroll
  for (int k = 0; k < 4; k++) {
    uint4 o1, o2;
    o1.x = words[k].x; o1.y = run; run += __popc(words[k].x);
    o1.z = words[k].y; o1.w = run; run += __popc(words[k].y);
    o2.x = words[k].z; o2.y = run; run += __popc(words[k].z);
    o2.z = words[k].w; o2.w = run; run += __popc(words[k].w);
    pp[2 * k] = o1;
    pp[2 * k + 1] = o2;
  }
}

// bit-decode of one word's set bits -> unique coors rows
template <int LZ, int LYZ, int LB, int MZ, int MY, int MX, int RG, int SCALE_IDX>
__device__ __forceinline__ void uniq_region(
    uint32_t w, uint32_t wd, uint32_t pf, uint32_t rankBase,
    const long long* __restrict__ devOff, int* __restrict__ out, long long fiveN) {
  uint32_t pos = pf - rankBase;
  long long base = devOff[SCALE_IDX] + fiveN;
  uint32_t local = w - (uint32_t)RG;
  while (wd) {
    int bit = __ffs(wd) - 1;
    wd &= wd - 1u;
    uint32_t key = (local << 5) + (uint32_t)bit;
    int z = (int)(key & (uint32_t)MZ);
    int y = (int)((key >> LZ) & (uint32_t)MY);
    int x = (int)((key >> LYZ) & (uint32_t)MX);
    int bb = (int)(key >> LB);
    *(int4*)(out + base + 4LL * pos) = make_int4(bb, z, y, x);
    pos++;
  }
}

// ---- merged per-point writes + unique decode (R7) ----
// blocks [0, 4*NW): full_coors+inverse, one scale per section (s1 first);
// blocks [4*NW, 4*NW+TOTALW/256): unique-row decode.
__global__ __launch_bounds__(256) void k_out(
    const uint32_t* __restrict__ keys, int n, const uint2* __restrict__ pairs,
    const uint32_t* __restrict__ devRank, const long long* __restrict__ devOff,
    int* __restrict__ out, long long fourN, long long fiveN, int NW) {
  int bid = blockIdx.x;
  int t = threadIdx.x;
  if (bid < 4 * NW) {
    int sec = bid / NW;
    int wb = bid - sec * NW;
    const int SCI[4] = {3, 0, 1, 2};  // section -> scale idx (s1 first)
    const int SX[4] = {256, 128, 64, 512};   // SY == SX for all scales
    const int SZ[4] = {32, 16, 8, 64};
    const int SH[4] = {1, 2, 3, 0};
    const int RG[4] = {R_S2, R_S4, R_S8, R_S1};
    int i = SCI[sec];
    int sh = SH[i], sx = SX[i], sz = SZ[i], rg = RG[i];
    long long o = devOff[i];
    uint32_t rnk = devRank[i];
#pragma unroll
    for (int half = 0; half < 2; half++) {
      int j = wb * 512 + half * 256 + t;
      if (j >= n) continue;
      uint32_t p = keys[j];
      int b = (int)(p >> 27);
      int x1 = (int)((p >> 17) & 1023u);
      int y1 = (int)((p >> 7) & 1023u);
      int z1 = (int)(p & 127u);
      int xi = x1 >> sh, yi = y1 >> sh, zi = z1 >> sh;
      uint32_t key = (uint32_t)(((b * sx + xi) * sx + yi) * sz + zi);
      uint2 pr = pairs[rg + (key >> 5)];
      *(int4*)(out + o + 4LL * j) = make_int4(b, xi, yi, zi);
      uint32_t inv = pr.y + __popc(pr.x & ((1u << (key & 31u)) - 1u)) - rnk;
      out[o + fourN + j] = (int)inv;
    }
  } else {
    uint32_t w = (uint32_t)(bid - 4 * NW) * 256 + t;  // < TOTALW, regions block-aligned
    uint2 pr = pairs[w];
    if (!pr.x) return;
    if (w < R_S4) {
      uniq_region<5, 13, 21, 31, 255, 255, R_S2, 0>(w, pr.x, pr.y, devRank[0], devOff, out, fiveN);
    } else if (w < R_S8) {
      uniq_region<4, 11, 18, 15, 127, 127, R_S4, 1>(w, pr.x, pr.y, devRank[1], devOff, out, fiveN);
    } else if (w < R_S1) {
      uniq_region<3, 9, 15, 7, 63, 63, R_S8, 2>(w, pr.x, pr.y, devRank[2], devOff, out, fiveN);
    } else {
      uniq_region<6, 15, 24, 63, 511, 511, R_S1, 3>(w, pr.x, pr.y, devRank[3], devOff, out, fiveN);
    }
  }
}

extern "C" void kernel_launch(void* const* d_in, const int* in_sizes, int n_in,
                              void* d_out, int out_size, void* d_ws, size_t ws_size,
                              hipStream_t stream) {
  const float* pts = (const float*)d_in[0];
  const int* bidx = (const int*)d_in[1];
  int n = in_sizes[0] / 3;
  int* out = (int*)d_out;

  char* ws = (char*)d_ws;
  long long* devOff = (long long*)ws;                          // 5 * 8 B
  uint32_t* devRank = (uint32_t*)(ws + 64);                    // 4 * 4 B
  uint32_t* chunkSums = (uint32_t*)(ws + 256);                 // NB * 4 B
  uint32_t* bucketCount = (uint32_t*)(ws + 5120);              // 512 * 4 B
  uint32_t* bitmap = (uint32_t*)(ws + 8192);                   // TOTALW * 4 B
  uint2* pairs = (uint2*)(ws + 19243008);                      // TOTALW * 8 B
  uint32_t* keys = (uint32_t*)(ws + 57712640);                 // n * 4 B
  uint32_t* bucketData = (uint32_t*)(ws + 65712640);           // 512 * BCAP * 4 B

  const long long fourN = 4LL * n, fiveN = 5LL * n;
  const int NW = (n + 511) / 512;

  hipMemsetAsync(bucketCount, 0, NBUCKET * 4, stream);
  hipLaunchKernelGGL(k_key, dim3(KEYBLOCKS), dim3(256), 0, stream,
                     pts, bidx, n, keys, bucketCount, bucketData, chunkSums);
  hipLaunchKernelGGL(k_bucket, dim3(NBUCKET), dim3(256), 0, stream,
                     bucketCount, bucketData, bitmap, chunkSums);
  hipLaunchKernelGGL(k_scanB, dim3(1), dim3(256), 0, stream, chunkSums, devOff, devRank, fiveN);
  hipLaunchKernelGGL(k_pref, dim3(NB), dim3(256), 0, stream, bitmap, chunkSums, pairs);
  hipLaunchKernelGGL(k_out, dim3(4 * NW + TOTALW / 256), dim3(256), 0, stream,
                     keys, n, pairs, devRank, devOff, out, fourN, fiveN, NW);
}